// Round 7
// baseline (378.105 us; speedup 1.0000x reference)
//
#include <hip/hip_runtime.h>
#include <stdint.h>

// Problem constants (from reference)
#define BATCH   2048
#define IN_BITS 4096
#define N_IN    2048
#define N_ST    1024
#define N_OUT   1024
#define KBITS   14
#define MROW    16384  // 2^14 floats per mem row (UNPACKED — gathered directly)
#define SROW    96     // s_inp/o_inp packed row words: 3072 bits

#define GS  524288     // grid: 2048 blocks * 256 threads

typedef float f32x4 __attribute__((ext_vector_type(4)));
typedef int   i32x4 __attribute__((ext_vector_type(4)));

// ---------------------------------------------------------------------------
// R7 design note. R6 counters (first direct ram-layer evidence): layer 1 =
// 79 us, FETCH 160 MB (= table read ~once: XCD-affine reuse works, HBM bytes
// near-minimal), 2.1 TB/s, VALUBusy 16%, occ 36% -> LATENCY-bound. The
// j-loop's unroll-4 kept only ~4 gathers in flight/lane. This version splits
// the lookup into 3 fully-unrolled phases: (1) all 16 addresses, (2) all 16
// independent gathers into a register array (nothing consumes between loads
// -> compiler must issue 16 back-to-back global_load_dword), (3) combine.
// ~32 extra VGPR, still <=128 -> occupancy unchanged (4 blocks/CU).
// This 2-3 TB/s latency cap killed every pack variant in R0-R5 too.
// ---------------------------------------------------------------------------

// Ballot-layout emit for input bits: from a loaded int4, form 4 ballots,
// lanes 0..7 store the chunk's 8 u32 words. Consumer remap for bit addr a:
//   word = ((a>>5)&~7) | ((a&3)<<1) | ((a>>7)&1);  shift = (a>>2)&31
__device__ __forceinline__ void emit1i(uint32_t* __restrict__ d, long i,
                                       int lane, i32x4 v) {
    unsigned long long b0 = __ballot(v[0] == 1);
    unsigned long long b1 = __ballot(v[1] == 1);
    unsigned long long b2 = __ballot(v[2] == 1);
    unsigned long long b3 = __ballot(v[3] == 1);
    if (lane < 8) {
        unsigned long long bj = (lane & 4) ? ((lane & 2) ? b3 : b2)
                                           : ((lane & 2) ? b1 : b0);
        uint32_t w = (lane & 1) ? (uint32_t)(bj >> 32) : (uint32_t)bj;
        d[((i >> 6) << 3) + lane] = w;
    }
}

// Pack input_bits (ballot layout -> bits1) and state_bits (linear layout ->
// buf_s words 64..95). 40 MB total read.
__global__ __launch_bounds__(256) void pack_in_st(const int* __restrict__ ib,
                                                  const int* __restrict__ sb,
                                                  uint32_t* __restrict__ bits1,
                                                  uint32_t* __restrict__ buf_s) {
    const long t = blockIdx.x * 256 + threadIdx.x;   // [0, GS)
    const int lane = threadIdx.x & 63;
    i32x4 wi[4];
#pragma unroll
    for (int u = 0; u < 4; ++u) wi[u] = ((const i32x4*)ib)[(long)u * GS + t];
    i32x4 wst = ((const i32x4*)sb)[t];
#pragma unroll
    for (int u = 0; u < 4; ++u) emit1i(bits1, (long)u * GS + t, lane, wi[u]);
    // state -> buf_s words 64..95, LINEAR layout (matches SROW consumers)
    uint32_t nib = (uint32_t)(wst[0] == 1) | ((uint32_t)(wst[1] == 1) << 1) |
                   ((uint32_t)(wst[2] == 1) << 2) | ((uint32_t)(wst[3] == 1) << 3);
    uint32_t w = nib << (4 * (lane & 7));
    w |= __shfl_xor(w, 1, 64);
    w |= __shfl_xor(w, 2, 64);
    w |= __shfl_xor(w, 4, 64);
    if ((lane & 7) == 0) {
        long g = t >> 3;          // global word index
        buf_s[(g >> 5) * SROW + 64 + (int)(g & 31)] = w;
    }
}

// ---------------------------------------------------------------------------
// TRANSPOSED RAM layer, direct float-table gather, 3-phase deep-MLP lookup.
// lane = batch (64/block), wave = 16-neuron group. conn wave-uniform (scalar
// loads); LDS reads via odd stride -> 2 lanes/bank (free); gather hits one
// 64KB float row per wave-instr; grid x = neuron-group -> XCD-affine
// (bid%8 == x%8) so each XCD's L2 holds its slice's rows across all
// batch-group blocks (FETCH 160MB in R6 confirms ~1x table read from HBM).
// MODE 0: h_in -> dst0,dst1 words 0..63   MODE 1: s_out -> dst0 words 64..95
// MODE 2: 16 bits/lane -> 4x float4 stores (64B line per lane)
template <int SRCW, int MODE>
__global__ __launch_bounds__(256) void ram_layer_g(const uint32_t* __restrict__ src,
                                                   const int* __restrict__ conn,
                                                   const float* __restrict__ memf,
                                                   uint32_t* __restrict__ dst0,
                                                   uint32_t* __restrict__ dst1,
                                                   float* __restrict__ fout) {
    constexpr int LSTR = SRCW + 1;           // odd -> conflict-free column reads
    __shared__ uint32_t lds[64 * LSTR];
    const int tid = threadIdx.x;
    const int b0 = blockIdx.y * 64;
    {
        const uint4* g = (const uint4*)(src + (long)b0 * SRCW);
        constexpr int NQ = 64 * SRCW / 4;
#pragma unroll
        for (int i = tid; i < NQ; i += 256) {
            uint4 v = g[i];
            int r = i / (SRCW / 4);
            int w = (i - r * (SRCW / 4)) * 4;
            uint32_t* p = &lds[r * LSTR + w];
            p[0] = v.x; p[1] = v.y; p[2] = v.z; p[3] = v.w;
        }
    }
    __syncthreads();
    const int lane = tid & 63;
    const int wave = __builtin_amdgcn_readfirstlane(tid >> 6);
    const int nw0 = blockIdx.x * 64 + wave * 16;
    const long b = b0 + lane;
    const uint32_t* row = lds + lane * LSTR;

    // Phase 1: all 16 addresses (LDS + scalar conn; no global loads).
    uint32_t addrs[16];
#pragma unroll
    for (int j = 0; j < 16; ++j) {
        const int* cp = conn + (nw0 + j) * KBITS;   // wave-uniform -> s_load
        uint32_t a = 0;
#pragma unroll
        for (int k = 0; k < KBITS; ++k) {
            int idx = cp[k];
            int wd, sh;
            if (SRCW == 128) {               // bits1 is ballot layout
                wd = ((idx >> 5) & ~7) | ((idx & 3) << 1) | ((idx >> 7) & 1);
                sh = (idx >> 2) & 31;
            } else {                         // SROW buffers are linear layout
                wd = idx >> 5;
                sh = idx & 31;
            }
            a = (a << 1) | ((row[wd] >> sh) & 1u);
        }
        addrs[j] = a;
    }
    // Phase 2: 16 independent gathers, nothing consumed in between ->
    // 16 global_load_dword in flight per lane (latency hiding).
    float vals[16];
#pragma unroll
    for (int j = 0; j < 16; ++j)
        vals[j] = memf[(long)(nw0 + j) * MROW + addrs[j]];
    // Phase 3: combine.
    uint32_t acc = 0;
#pragma unroll
    for (int j = 0; j < 16; ++j)
        acc |= ((vals[j] == 1.0f) ? 1u : 0u) << j;

    if (MODE == 2) {
        float* op = fout + b * N_OUT + nw0;  // 16 consecutive floats = 64B
#pragma unroll
        for (int q = 0; q < 4; ++q) {
            f32x4 f;
#pragma unroll
            for (int e = 0; e < 4; ++e) f[e] = (float)((acc >> (q * 4 + e)) & 1u);
            ((f32x4*)op)[q] = f;
        }
    } else {
        const int woff = (MODE == 0 ? 0 : 64) + (nw0 >> 5);
        const int half = (nw0 >> 4) & 1;
        ((ushort*)(dst0 + b * SROW + woff))[half] = (ushort)acc;
        if (MODE == 0)
            ((ushort*)(dst1 + b * SROW + woff))[half] = (ushort)acc;
    }
}

// ---------------------------------------------------------------------------
extern "C" void kernel_launch(void* const* d_in, const int* in_sizes, int n_in,
                              void* d_out, int out_size, void* d_ws, size_t ws_size,
                              hipStream_t stream) {
    const int*   input_bits = (const int*)d_in[0];
    const int*   state_bits = (const int*)d_in[1];
    const int*   in_conn    = (const int*)d_in[2];
    const float* in_mem     = (const float*)d_in[3];
    const int*   st_conn    = (const int*)d_in[4];
    const float* st_mem     = (const float*)d_in[5];
    const int*   out_conn   = (const int*)d_in[6];
    const float* out_mem    = (const float*)d_in[7];
    float*       out        = (float*)d_out;

    // Workspace layout (all 256B-aligned):
    //   bits1 : [B][128] u32  = 1 MB   (packed input_bits, ballot layout)
    //   buf_s : [B][96]  u32  = 768 KB (s_inp bits: h_in | state, linear)
    //   buf_o : [B][96]  u32  = 768 KB (o_inp bits: h_in | s_out, linear)
    //   (mem tables are NOT packed — gathered directly as floats)
    char* ws = (char*)d_ws;
    uint32_t* bits1 = (uint32_t*)(ws);
    uint32_t* buf_s = (uint32_t*)(ws + 1048576);
    uint32_t* buf_o = (uint32_t*)(ws + 1048576 + 786432);

    pack_in_st<<<2048, 256, 0, stream>>>(input_bits, state_bits, bits1, buf_s);
    // Layer 1: input_bits -> h_in (into both buf_s and buf_o, words 0..63)
    ram_layer_g<128, 0><<<dim3(N_IN / 64, BATCH / 64), 256, 0, stream>>>(
        bits1, in_conn, in_mem, buf_s, buf_o, nullptr);
    // Layer 2: s_inp -> s_out (into buf_o words 64..95)
    ram_layer_g<SROW, 1><<<dim3(N_ST / 64, BATCH / 64), 256, 0, stream>>>(
        buf_s, st_conn, st_mem, buf_o, nullptr, nullptr);
    // Layer 3: o_inp -> output floats
    ram_layer_g<SROW, 2><<<dim3(N_OUT / 64, BATCH / 64), 256, 0, stream>>>(
        buf_o, out_conn, out_mem, nullptr, nullptr, out);
}

// Round 9
// 361.772 us; speedup vs baseline: 1.0451x; 1.0451x over previous
//
#include <hip/hip_runtime.h>
#include <stdint.h>

// Problem constants (from reference)
#define BATCH   2048
#define IN_BITS 4096
#define N_IN    2048
#define N_ST    1024
#define N_OUT   1024
#define KBITS   14
#define MW      512   // 2^14 bits / 32 = words per packed mem row
#define SROW    96    // s_inp/o_inp packed row words: 3072 bits

typedef float f32x4 __attribute__((ext_vector_type(4)));
typedef int   i32x4 __attribute__((ext_vector_type(4)));

// ---------------------------------------------------------------------------
// R9 = R8 with the vmcnt ledger bug fixed.
// R8 failed because the FINAL step waited vmcnt(8) while only 8 ops
// (needed-load L8 x4 + stores S7 x4) were outstanding -> wait satisfied
// without L8 retiring -> bits1 read before DMA landed. vmcnt counts loads
// AND stores on GFX9-lineage; the per-step ledger is:
//   L0 L1 [wait] S0 L2 [wait] S1 L3 [wait] ... S6 L8 [wait] S7 [wait:tail]
// Using vmcnt(4) at EVERY wait is correct under both "stores count" and
// "stores don't count" semantics: it retires everything except the 4
// newest ops, and the 4 newest are always the just-issued prefetch batch
// (or the final stores), so the needed load batch is always retired.
// ---------------------------------------------------------------------------

__device__ __forceinline__ void emit1f(uint32_t* __restrict__ d, long gi,
                                       int lane, f32x4 v) {
    unsigned long long b0 = __ballot(v[0] == 1.0f);
    unsigned long long b1 = __ballot(v[1] == 1.0f);
    unsigned long long b2 = __ballot(v[2] == 1.0f);
    unsigned long long b3 = __ballot(v[3] == 1.0f);
    if (lane < 8) {
        unsigned long long bj = (lane & 4) ? ((lane & 2) ? b3 : b2)
                                           : ((lane & 2) ? b1 : b0);
        uint32_t w = (lane & 1) ? (uint32_t)(bj >> 32) : (uint32_t)bj;
        d[((gi >> 6) << 3) + lane] = w;
    }
}
__device__ __forceinline__ void emit1i(uint32_t* __restrict__ d, long gi,
                                       int lane, i32x4 v) {
    unsigned long long b0 = __ballot(v[0] == 1);
    unsigned long long b1 = __ballot(v[1] == 1);
    unsigned long long b2 = __ballot(v[2] == 1);
    unsigned long long b3 = __ballot(v[3] == 1);
    if (lane < 8) {
        unsigned long long bj = (lane & 4) ? ((lane & 2) ? b3 : b2)
                                           : ((lane & 2) ? b1 : b0);
        uint32_t w = (lane & 1) ? (uint32_t)(bj >> 32) : (uint32_t)bj;
        d[((gi >> 6) << 3) + lane] = w;
    }
}

// DMA-staged pack of ALL inputs in one dispatch.
// 2048 blocks x 4 waves = 8192 wave-slots. Per slot, 9 x 4KB batches:
// steps 0-3 im, 4-5 sm, 6-7 om, 8 input_bits. Each batch = 4 DMA calls of
// 1KB (64 lanes x 16B) into the wave's LDS slice; double-buffered.
__global__ __launch_bounds__(256) void pack_dma(
    const uint32_t* __restrict__ im, const uint32_t* __restrict__ sm,
    const uint32_t* __restrict__ om, const uint32_t* __restrict__ ib,
    const int* __restrict__ sb,
    uint32_t* __restrict__ im_p, uint32_t* __restrict__ sm_p,
    uint32_t* __restrict__ om_p, uint32_t* __restrict__ bits1,
    uint32_t* __restrict__ buf_s) {
    __shared__ uint32_t sbuf[4][2][1024];   // 32 KB: per-wave 2 x 4KB
    const int tid  = threadIdx.x;
    const int lane = tid & 63;
    const int w    = tid >> 6;
    const long slot = blockIdx.x * 4 + w;   // [0, 8192)

    const uint32_t* srcs[9] = { im, im, im, im, sm, sm, om, om, ib };
    uint32_t*       dsts[9] = { im_p, im_p, im_p, im_p, sm_p, sm_p,
                                om_p, om_p, bits1 };
    const long      bats[9] = { slot, slot + 8192, slot + 16384, slot + 24576,
                                slot, slot + 8192, slot, slot + 8192, slot };

    auto issue = [&](int s, int pp) {
        const uint32_t* tab = srcs[s];
        const long base = bats[s] * 1024;       // words
#pragma unroll
        for (int q = 0; q < 4; ++q)
            __builtin_amdgcn_global_load_lds(
                (const __attribute__((address_space(1))) uint32_t*)
                    (tab + base + q * 256 + lane * 4),
                (__attribute__((address_space(3))) uint32_t*)
                    (&sbuf[w][pp][q * 256]),
                16, 0, 0);
    };

    issue(0, 0);
    issue(1, 1);
#pragma unroll
    for (int s = 0; s < 9; ++s) {
        // vmcnt(4): retire all but the 4 newest VMEM ops (= the batch
        // issued last); correct whether or not stores count in vmcnt.
        asm volatile("s_waitcnt vmcnt(4)" ::: "memory");
        const int pp = s & 1;
        const long b = bats[s];
        uint32_t* d = dsts[s];
#pragma unroll
        for (int q = 0; q < 4; ++q) {
            const long gi = b * 256 + q * 64 + lane;   // float4/int4 index
            if (s < 8) {
                f32x4 v = *(const f32x4*)&sbuf[w][pp][q * 256 + lane * 4];
                emit1f(d, gi, lane, v);
            } else {
                i32x4 v = *(const i32x4*)&sbuf[w][pp][q * 256 + lane * 4];
                emit1i(d, gi, lane, v);
            }
        }
        if (s + 2 < 9) issue(s + 2, pp);
    }

    // Tail: state_bits (8 MB) -> buf_s words 64..95, LINEAR layout.
    {
        const long t = (long)blockIdx.x * 256 + tid;   // int4 index
        i32x4 v = ((const i32x4*)sb)[t];
        uint32_t nib = (uint32_t)(v[0] == 1) | ((uint32_t)(v[1] == 1) << 1) |
                       ((uint32_t)(v[2] == 1) << 2) | ((uint32_t)(v[3] == 1) << 3);
        uint32_t wv = nib << (4 * (lane & 7));
        wv |= __shfl_xor(wv, 1, 64);
        wv |= __shfl_xor(wv, 2, 64);
        wv |= __shfl_xor(wv, 4, 64);
        if ((lane & 7) == 0) {
            long g = t >> 3;
            buf_s[(g >> 5) * SROW + 64 + (int)(g & 31)] = wv;
        }
    }
}

// ---------------------------------------------------------------------------
// TRANSPOSED RAM layer (R3, proven). lane = batch (64/block), wave =
// 16-neuron group. conn wave-uniform (scalar loads); LDS reads via odd
// stride -> 2 lanes/bank (free); gather reads one 2KB packed row per
// wave-instr; grid x = neuron group -> XCD-affine.
// MODE 0: h_in -> dst0,dst1 words 0..63   MODE 1: s_out -> dst0 words 64..95
// MODE 2: floats -> fout
template <int SRCW, int MODE>
__global__ __launch_bounds__(256) void ram_layer_t(const uint32_t* __restrict__ src,
                                                   const int* __restrict__ conn,
                                                   const uint32_t* __restrict__ memp,
                                                   uint32_t* __restrict__ dst0,
                                                   uint32_t* __restrict__ dst1,
                                                   float* __restrict__ fout) {
    constexpr int LSTR = SRCW + 1;           // odd -> conflict-free column reads
    __shared__ uint32_t lds[64 * LSTR];
    const int tid = threadIdx.x;
    const int b0 = blockIdx.y * 64;
    {
        const uint4* g = (const uint4*)(src + (long)b0 * SRCW);
        constexpr int NQ = 64 * SRCW / 4;
#pragma unroll
        for (int i = tid; i < NQ; i += 256) {
            uint4 v = g[i];
            int r = i / (SRCW / 4);
            int w = (i - r * (SRCW / 4)) * 4;
            uint32_t* p = &lds[r * LSTR + w];
            p[0] = v.x; p[1] = v.y; p[2] = v.z; p[3] = v.w;
        }
    }
    __syncthreads();
    const int lane = tid & 63;
    const int wave = __builtin_amdgcn_readfirstlane(tid >> 6);
    const int nw0 = blockIdx.x * 64 + wave * 16;
    const long b = b0 + lane;
    const uint32_t* row = lds + lane * LSTR;
    uint32_t acc = 0;
#pragma unroll 2
    for (int j = 0; j < 16; ++j) {
        const int n = nw0 + j;
        const int* cp = conn + n * KBITS;
        uint32_t addr = 0;
#pragma unroll
        for (int k = 0; k < KBITS; ++k) {
            int idx = cp[k];
            int wd, sh;
            if (SRCW == 128) {               // bits1 is ballot layout
                wd = ((idx >> 5) & ~7) | ((idx & 3) << 1) | ((idx >> 7) & 1);
                sh = (idx >> 2) & 31;
            } else {                         // SROW buffers are linear layout
                wd = idx >> 5;
                sh = idx & 31;
            }
            addr = (addr << 1) | ((row[wd] >> sh) & 1u);
        }
        // mem tables are ballot layout: remap bit address -> (word, shift)
        uint32_t mw = ((addr >> 5) & ~7u) | ((addr & 3u) << 1) | ((addr >> 7) & 1u);
        uint32_t bit = (memp[(long)n * MW + mw] >> ((addr >> 2) & 31u)) & 1u;
        if (MODE == 2) fout[b * N_OUT + n] = (float)bit;
        else           acc |= bit << j;
    }
    if (MODE != 2) {
        const int woff = (MODE == 0 ? 0 : 64) + (nw0 >> 5);
        const int half = (nw0 >> 4) & 1;
        ((ushort*)(dst0 + b * SROW + woff))[half] = (ushort)acc;
        if (MODE == 0)
            ((ushort*)(dst1 + b * SROW + woff))[half] = (ushort)acc;
    }
}

// ---------------------------------------------------------------------------
extern "C" void kernel_launch(void* const* d_in, const int* in_sizes, int n_in,
                              void* d_out, int out_size, void* d_ws, size_t ws_size,
                              hipStream_t stream) {
    const int*   input_bits = (const int*)d_in[0];
    const int*   state_bits = (const int*)d_in[1];
    const int*   in_conn    = (const int*)d_in[2];
    const float* in_mem     = (const float*)d_in[3];
    const int*   st_conn    = (const int*)d_in[4];
    const float* st_mem     = (const float*)d_in[5];
    const int*   out_conn   = (const int*)d_in[6];
    const float* out_mem    = (const float*)d_in[7];
    float*       out        = (float*)d_out;

    // Workspace layout (all 256B-aligned):
    //   bits1 : [B][128] u32  = 1 MB   (packed input_bits, ballot layout)
    //   buf_s : [B][96]  u32  = 768 KB (s_inp bits: h_in | state, linear)
    //   buf_o : [B][96]  u32  = 768 KB (o_inp bits: h_in | s_out, linear)
    //   im_p  : [2048][512]   = 4 MB   (ballot layout)
    //   sm_p  : [1024][512]   = 2 MB   (ballot layout)
    //   om_p  : [1024][512]   = 2 MB   (ballot layout)
    char* ws = (char*)d_ws;
    uint32_t* bits1 = (uint32_t*)(ws);
    uint32_t* buf_s = (uint32_t*)(ws + 1048576);
    uint32_t* buf_o = (uint32_t*)(ws + 1048576 + 786432);
    uint32_t* im_p  = (uint32_t*)(ws + 1048576 + 2 * 786432);
    uint32_t* sm_p  = (uint32_t*)(ws + 1048576 + 2 * 786432 + 4194304);
    uint32_t* om_p  = (uint32_t*)(ws + 1048576 + 2 * 786432 + 4194304 + 2097152);

    // One DMA-staged packing pass, then the three RAM layers.
    pack_dma<<<2048, 256, 0, stream>>>(
        (const uint32_t*)in_mem, (const uint32_t*)st_mem,
        (const uint32_t*)out_mem, (const uint32_t*)input_bits, state_bits,
        im_p, sm_p, om_p, bits1, buf_s);
    ram_layer_t<128, 0><<<dim3(N_IN / 64, BATCH / 64), 256, 0, stream>>>(
        bits1, in_conn, im_p, buf_s, buf_o, nullptr);
    ram_layer_t<SROW, 1><<<dim3(N_ST / 64, BATCH / 64), 256, 0, stream>>>(
        buf_s, st_conn, sm_p, buf_o, nullptr, nullptr);
    ram_layer_t<SROW, 2><<<dim3(N_OUT / 64, BATCH / 64), 256, 0, stream>>>(
        buf_o, out_conn, om_p, nullptr, nullptr, out);
}

// Round 10
// 336.630 us; speedup vs baseline: 1.1232x; 1.0747x over previous
//
#include <hip/hip_runtime.h>
#include <stdint.h>

// ============================================================================
// FINAL (R10) = byte-identical revert to the session-best R2 artifact
// (336.47 us measured). Roofline argument:
//   dur_us = 233 us harness re-poison fills (3 x 512 MB writes, not
//            controllable from kernel side)
//          + ~90 us mandatory d_in read: 296 MB at the ~3.5 TB/s read-path
//            ceiling. Seven structurally independent read mechanisms
//            (one-shot, grid-stride+NT, reg-batched, fused-coop, interleaved
//            gather, deep-MLP gather, global_load_lds DMA) all pinned at
//            2.1-3.6 TB/s; an L3-resident replay (FETCH~0) was equally slow
//            -> path property of the d_in allocations, not kernel structure.
//          + ~15-20 us RAM layers on packed tables (near their LDS/L2 floor).
// ============================================================================

#define BATCH   2048
#define IN_BITS 4096
#define N_IN    2048
#define N_ST    1024
#define N_OUT   1024
#define KBITS   14
#define MW      512   // 2^14 bits / 32 = words per packed mem row
#define SROW    96    // s_inp/o_inp packed row words: 3072 bits

#define IM4 8388608   // N_IN * 16384 / 4
#define SM4 4194304
#define OM4 4194304
#define GS  524288    // grid-stride: 2048 blocks * 256 threads

typedef float f32x4 __attribute__((ext_vector_type(4)));
typedef int   i32x4 __attribute__((ext_vector_type(4)));

// Ballot-layout bit pack, grid-strided. Layout per 256-bit chunk c ->
// words [8c..8c+7]; consumer remap for bit address a:
//   word = ((a>>5) & ~7) | ((a&3)<<1) | ((a>>7)&1);  shift = (a>>2)&31
__global__ __launch_bounds__(256) void pack_mem_all(const float* __restrict__ im,
                                                    const float* __restrict__ sm,
                                                    const float* __restrict__ om,
                                                    uint32_t* __restrict__ im_p,
                                                    uint32_t* __restrict__ sm_p,
                                                    uint32_t* __restrict__ om_p) {
    const int t = blockIdx.x * 256 + threadIdx.x;   // [0, GS)
    const int lane = threadIdx.x & 63;
#pragma unroll
    for (int c = 0; c < 32; ++c) {
        const float* s; uint32_t* d; int cl;
        if (c < 16)      { s = im; d = im_p; cl = c; }
        else if (c < 24) { s = sm; d = sm_p; cl = c - 16; }
        else             { s = om; d = om_p; cl = c - 24; }
        const long i = (long)cl * GS + t;            // float4 index within table
        f32x4 v = __builtin_nontemporal_load((const f32x4*)s + i);
        unsigned long long b0 = __ballot(v[0] == 1.0f);
        unsigned long long b1 = __ballot(v[1] == 1.0f);
        unsigned long long b2 = __ballot(v[2] == 1.0f);
        unsigned long long b3 = __ballot(v[3] == 1.0f);
        if (lane < 8) {
            unsigned long long bj = (lane & 4) ? ((lane & 2) ? b3 : b2)
                                               : ((lane & 2) ? b1 : b0);
            uint32_t w = (lane & 1) ? (uint32_t)(bj >> 32) : (uint32_t)bj;
            d[((i >> 6) << 3) + lane] = w;   // 8 lanes -> 32B contiguous
        }
    }
}

// Ballot-layout pack of input_bits (rows = 4096 bits = 16 chunks, 128 words).
__global__ __launch_bounds__(256) void pack_input(const int* __restrict__ src,
                                                  uint32_t* __restrict__ dst) {
    const int t = blockIdx.x * 256 + threadIdx.x;   // [0, GS)
    const int lane = threadIdx.x & 63;
#pragma unroll
    for (int c = 0; c < 4; ++c) {
        const long i = (long)c * GS + t;            // int4 index
        i32x4 v = __builtin_nontemporal_load((const i32x4*)src + i);
        unsigned long long b0 = __ballot(v[0] == 1);
        unsigned long long b1 = __ballot(v[1] == 1);
        unsigned long long b2 = __ballot(v[2] == 1);
        unsigned long long b3 = __ballot(v[3] == 1);
        if (lane < 8) {
            unsigned long long bj = (lane & 4) ? ((lane & 2) ? b3 : b2)
                                               : ((lane & 2) ? b1 : b0);
            uint32_t w = (lane & 1) ? (uint32_t)(bj >> 32) : (uint32_t)bj;
            dst[((i >> 6) << 3) + lane] = w;
        }
    }
}

// Coalesced pack of state_bits into buf_s at word offset 64, row stride SROW.
// LINEAR layout (matches ram_layer's ballot writes for words 0..63).
__global__ __launch_bounds__(256) void pack_state(const int4* __restrict__ src,
                                                  uint32_t* __restrict__ dst) {
    int t = blockIdx.x * 256 + threadIdx.x;  // one int4 per thread; row = 1024 bits
    int4 v = src[t];
    uint32_t nib = (uint32_t)(v.x == 1) | ((uint32_t)(v.y == 1) << 1) |
                   ((uint32_t)(v.z == 1) << 2) | ((uint32_t)(v.w == 1) << 3);
    int lane = threadIdx.x & 63;
    uint32_t w = nib << (4 * (lane & 7));
    w |= __shfl_xor(w, 1, 64);
    w |= __shfl_xor(w, 2, 64);
    w |= __shfl_xor(w, 4, 64);
    if ((lane & 7) == 0) {
        int g = t >> 3;          // global word index
        int r = g >> 5;          // 32 words per row
        int c = g & 31;
        dst[(long)r * SROW + 64 + c] = w;
    }
}

// RAM layer: lane = neuron (64 consecutive per wave), block stages BCHUNK
// packed batch rows in LDS. Per (b,n): gather 14 bits from LDS -> 14-bit
// address (k=0 is MSB) -> 1 gather into the packed mem row (ballot remap).
// MODE 0: ballot bits -> dst0,dst1 words 0..63 (stride SROW)
// MODE 1: ballot bits -> dst0 words 64..95
// MODE 2: floats -> fout [b*N_OUT + n]
template <int SRCW, int BCHUNK, int MODE>
__global__ __launch_bounds__(256) void ram_layer(const uint32_t* __restrict__ src,
                                                 const int* __restrict__ conn,
                                                 const uint32_t* __restrict__ memp,
                                                 uint32_t* __restrict__ dst0,
                                                 uint32_t* __restrict__ dst1,
                                                 float* __restrict__ fout) {
    __shared__ uint32_t lds[BCHUNK * SRCW];
    const int tid = threadIdx.x;
    const int b0 = blockIdx.y * BCHUNK;

    {
        const uint4* g = (const uint4*)(src + (long)b0 * SRCW);
        uint4* l = (uint4*)lds;
        constexpr int NV = BCHUNK * SRCW / 4;
        for (int i = tid; i < NV; i += 256) l[i] = g[i];
    }
    __syncthreads();

    const int n = blockIdx.x * 256 + tid;
    int wd[KBITS], sh[KBITS];
#pragma unroll
    for (int k = 0; k < KBITS; k++) {
        int idx = conn[n * KBITS + k];
        if (SRCW == 128) {
            wd[k] = ((idx >> 5) & ~7) | ((idx & 3) << 1) | ((idx >> 7) & 1);
            sh[k] = (idx >> 2) & 31;
        } else {
            wd[k] = idx >> 5;
            sh[k] = idx & 31;
        }
    }
    const uint32_t* mrow = memp + (long)n * MW;
    const int lane = tid & 63;
    const int nbase = blockIdx.x * 256 + (tid & ~63);  // wave's neuron base

#pragma unroll 4
    for (int bb = 0; bb < BCHUNK; ++bb) {
        const uint32_t* row = lds + bb * SRCW;
        uint32_t addr = 0;
#pragma unroll
        for (int k = 0; k < KBITS; k++)
            addr = (addr << 1) | ((row[wd[k]] >> sh[k]) & 1u);
        uint32_t mw = ((addr >> 5) & ~7u) | ((addr & 3u) << 1) | ((addr >> 7) & 1u);
        uint32_t bit = (mrow[mw] >> ((addr >> 2) & 31u)) & 1u;
        const int b = b0 + bb;
        if (MODE == 2) {
            fout[(long)b * N_OUT + n] = (float)bit;
        } else {
            unsigned long long m = __ballot(bit != 0);
            if (lane == 0) {
                if (MODE == 0) {
                    *(unsigned long long*)(dst0 + (long)b * SROW + (nbase >> 5)) = m;
                    *(unsigned long long*)(dst1 + (long)b * SROW + (nbase >> 5)) = m;
                } else {
                    *(unsigned long long*)(dst0 + (long)b * SROW + 64 + (nbase >> 5)) = m;
                }
            }
        }
    }
}

// ---------------------------------------------------------------------------
extern "C" void kernel_launch(void* const* d_in, const int* in_sizes, int n_in,
                              void* d_out, int out_size, void* d_ws, size_t ws_size,
                              hipStream_t stream) {
    const int*   input_bits = (const int*)d_in[0];
    const int*   state_bits = (const int*)d_in[1];
    const int*   in_conn    = (const int*)d_in[2];
    const float* in_mem     = (const float*)d_in[3];
    const int*   st_conn    = (const int*)d_in[4];
    const float* st_mem     = (const float*)d_in[5];
    const int*   out_conn   = (const int*)d_in[6];
    const float* out_mem    = (const float*)d_in[7];
    float*       out        = (float*)d_out;

    // Workspace layout (all 256B-aligned):
    //   bits1 : [B][128] u32  = 1 MB   (packed input_bits, ballot layout)
    //   buf_s : [B][96]  u32  = 768 KB (s_inp bits: h_in | state, linear)
    //   buf_o : [B][96]  u32  = 768 KB (o_inp bits: h_in | s_out, linear)
    //   im_p  : [2048][512]   = 4 MB   (ballot layout)
    //   sm_p  : [1024][512]   = 2 MB   (ballot layout)
    //   om_p  : [1024][512]   = 2 MB   (ballot layout)
    char* ws = (char*)d_ws;
    uint32_t* bits1 = (uint32_t*)(ws);
    uint32_t* buf_s = (uint32_t*)(ws + 1048576);
    uint32_t* buf_o = (uint32_t*)(ws + 1048576 + 786432);
    uint32_t* im_p  = (uint32_t*)(ws + 1048576 + 2 * 786432);
    uint32_t* sm_p  = (uint32_t*)(ws + 1048576 + 2 * 786432 + 4194304);
    uint32_t* om_p  = (uint32_t*)(ws + 1048576 + 2 * 786432 + 4194304 + 2097152);

    // Bit-pack inputs (ballot layout; grid-strided).
    pack_input<<<2048, 256, 0, stream>>>(input_bits, bits1);
    pack_state<<<(BATCH * N_ST / 4) / 256, 256, 0, stream>>>((const int4*)state_bits, buf_s);
    pack_mem_all<<<2048, 256, 0, stream>>>(in_mem, st_mem, out_mem, im_p, sm_p, om_p);

    // Layer 1: input_bits -> h_in (into both buf_s and buf_o, words 0..63)
    ram_layer<128, 16, 0><<<dim3(N_IN / 256, BATCH / 16), 256, 0, stream>>>(
        bits1, in_conn, im_p, buf_s, buf_o, nullptr);
    // Layer 2: s_inp -> s_out (into buf_o words 64..95)
    ram_layer<SROW, 8, 1><<<dim3(N_ST / 256, BATCH / 8), 256, 0, stream>>>(
        buf_s, st_conn, sm_p, buf_o, nullptr, nullptr);
    // Layer 3: o_inp -> output floats
    ram_layer<SROW, 8, 2><<<dim3(N_OUT / 256, BATCH / 8), 256, 0, stream>>>(
        buf_o, out_conn, om_p, nullptr, nullptr, out);
}